// Round 15
// baseline (33.771 us; speedup 1.0000x reference)
//
#include <hip/hip_runtime.h>
#include <hip/hip_bf16.h>

// EdgeNetwork: B=8, N=256, F_IN=64, F_OUT=64, MID=96
// out[b,n,o] = sum_m tanh( relu( [x_n, x_j(m), e_{b,n,m}] @ W1 + b1 ) @ W2 + b2 )[o]
// H[m,:] = A[b,n,:] + C[b,j(m),:] + e[m]*W1[128,:],  j = m + (m>=n)
// R15: prologue amortization. 512-thread blocks (8 waves), NG=8 n's per block,
// grid 256 = 1 block/CU = 8 waves/CU (occupancy unchanged vs R14). Phase B
// (C-GEMM), phase C (A rows), and all per-lane fragment loads now run half as
// often device-wide; main-loop work per wave identical (2 tiles/nl x 8 nl).
// tanh(v) = 1 - 2r, r = 1/(1+exp(2v));  out = 256 - 2*sum(r), invalid -> 0.5.

#define BATCH 8
#define NN 256
#define FIN 64
#define FOUT 64
#define MIDD 96
#define CPAD 104   // bf16 elems per padded sC row (208 B)
#define NG 8       // n-values per block

typedef __attribute__((ext_vector_type(8))) short short8;  // 8 bf16
typedef __attribute__((ext_vector_type(4))) float f32x4;
typedef __attribute__((ext_vector_type(2))) float f32x2;

#if __has_builtin(__builtin_amdgcn_exp2f)
#define EXP2F(x) __builtin_amdgcn_exp2f(x)
#else
#define EXP2F(x) exp2f(x)
#endif
#if __has_builtin(__builtin_amdgcn_rcpf)
#define RCPF(x) __builtin_amdgcn_rcpf(x)
#else
#define RCPF(x) (1.0f / (x))
#endif

#define TWO_LOG2E 2.8853900817779268f

__device__ __forceinline__ f32x2 pk_add(f32x2 a, f32x2 b) {
    f32x2 d;
    asm("v_pk_add_f32 %0, %1, %2" : "=v"(d) : "v"(a), "v"(b));
    return d;
}
__device__ __forceinline__ f32x2 pk_fma(f32x2 a, f32x2 b, f32x2 c) {
    f32x2 d;
    asm("v_pk_fma_f32 %0, %1, %2, %3" : "=v"(d) : "v"(a), "v"(b), "v"(c));
    return d;
}

__device__ __forceinline__ unsigned pack_bf16(float lo, float hi) {
    __hip_bfloat162 h2 = __float22bfloat162_rn(make_float2(lo, hi));
    union { __hip_bfloat162 h; unsigned u; } cv; cv.h = h2;
    return cv.u;
}
__device__ __forceinline__ unsigned short bf16_bits(float v) {
    union { __hip_bfloat16 h; unsigned short u; } cv;
    cv.h = __float2bfloat16(v);
    return cv.u;
}

// ---------------- single fused kernel, 512 threads ----------------------------
__global__ __launch_bounds__(512, 2) void edge_fused8(
    const float* __restrict__ node,   // (B,N,64)
    const float* __restrict__ edge,   // (B,N,255)
    const float* __restrict__ W1,     // (129,96)
    const float* __restrict__ b1,     // (96,)
    const float* __restrict__ W2,     // (96,64)
    const float* __restrict__ b2,     // (64,)
    float* __restrict__ out)          // (B,N,64)
{
    __shared__ unsigned short sC[NN * CPAD];   // 53248 B; tail reused for reduce
    __shared__ float sX[NG][FIN];              // 2048 B: x rows n0..n0+7
    __shared__ float sA[NG][MIDD];             // 3072 B: A rows n0..n0+7

    int blk = blockIdx.x;             // 0..255
    int b = blk >> 5;
    int n0 = (blk & 31) << 3;
    int tid = threadIdx.x;            // 0..511
    int w = tid >> 6;                 // wave 0..7
    int lane = tid & 63;
    int lo16 = lane & 15, hi = lane >> 4;

    // ---- x-row staging (one row per wave) ----
    sX[w][lane] = node[((size_t)b * NN + n0 + w) * FIN + lane];

    // ---- phase B: C[b] = node[b] @ W1[64:128] via MFMA -> sC (bf16) ----
    {
        // B-fragments of W1b: wb[ks2][ct], elem i = W1[64+ks2*32+hi*8+i][ct*16+lo16]
        short8 wb[2][6];
#pragma unroll
        for (int ks2 = 0; ks2 < 2; ++ks2)
#pragma unroll
            for (int ct = 0; ct < 6; ++ct) {
                float v[8];
#pragma unroll
                for (int i = 0; i < 8; ++i)
                    v[i] = W1[(size_t)(FIN + ks2 * 32 + hi * 8 + i) * MIDD + ct * 16 + lo16];
                union { unsigned u[4]; short8 s8; } cv;
                cv.u[0] = pack_bf16(v[0], v[1]);
                cv.u[1] = pack_bf16(v[2], v[3]);
                cv.u[2] = pack_bf16(v[4], v[5]);
                cv.u[3] = pack_bf16(v[6], v[7]);
                wb[ks2][ct] = cv.s8;
            }

        const float* nb = node + (size_t)b * NN * FIN;
#pragma unroll
        for (int rt = 0; rt < 2; ++rt) {
            int rtile = rt * 8 + w;           // 0..15, unique per wave
            int row = rtile * 16 + lo16;
            short8 xa[2];
#pragma unroll
            for (int ks2 = 0; ks2 < 2; ++ks2) {
                const float* xr = nb + (size_t)row * FIN + ks2 * 32 + hi * 8;
                float4 x0 = *(const float4*)(xr);
                float4 x1 = *(const float4*)(xr + 4);
                union { unsigned u[4]; short8 s8; } cv;
                cv.u[0] = pack_bf16(x0.x, x0.y);
                cv.u[1] = pack_bf16(x0.z, x0.w);
                cv.u[2] = pack_bf16(x1.x, x1.y);
                cv.u[3] = pack_bf16(x1.z, x1.w);
                xa[ks2] = cv.s8;
            }
            f32x4 acc6[6] = {{0.f,0.f,0.f,0.f},{0.f,0.f,0.f,0.f},{0.f,0.f,0.f,0.f},
                             {0.f,0.f,0.f,0.f},{0.f,0.f,0.f,0.f},{0.f,0.f,0.f,0.f}};
#pragma unroll
            for (int ks2 = 0; ks2 < 2; ++ks2)
#pragma unroll
                for (int ct = 0; ct < 6; ++ct)
                    acc6[ct] = __builtin_amdgcn_mfma_f32_16x16x32_bf16(
                        xa[ks2], wb[ks2][ct], acc6[ct], 0, 0, 0);
            // D: row = rtile*16 + hi*4 + r, col = ct*16 + lo16
#pragma unroll
            for (int ct = 0; ct < 6; ++ct)
#pragma unroll
                for (int r = 0; r < 4; ++r)
                    sC[(size_t)(rtile * 16 + hi * 4 + r) * CPAD + ct * 16 + lo16] =
                        bf16_bits(acc6[ct][r]);
        }
    }

    __syncthreads();   // sX + sC ready

    // ---- phase C: A rows: sA[nl][c] = x_{n0+nl} . W1[:64,c] + b1[c] ----
    {
#pragma unroll
        for (int it = 0; it < 2; ++it) {
            int idx = it * 512 + tid;
            if (idx < NG * MIDD) {
                int nl = idx / MIDD, c = idx % MIDD;
                float a0 = 0.f, a1 = 0.f;
#pragma unroll
                for (int f = 0; f < FIN; f += 2) {
                    a0 = fmaf(sX[nl][f],     W1[(size_t)f * MIDD + c],       a0);
                    a1 = fmaf(sX[nl][f + 1], W1[(size_t)(f + 1) * MIDD + c], a1);
                }
                sA[nl][c] = a0 + a1 + b1[c];
            }
        }
    }

    // ---- per-lane constants for the main loop ----
    f32x2 W2p[12];   // W1[128] slices as f32 pairs
    {
        const float* Wbase = W1 + 128 * MIDD;
#pragma unroll
        for (int ks = 0; ks < 3; ++ks) {
            int k0 = ks * 32 + hi * 8;
            float4 w0 = *(const float4*)(Wbase + k0);
            float4 w1 = *(const float4*)(Wbase + k0 + 4);
            W2p[ks*4+0] = f32x2{w0.x, w0.y};
            W2p[ks*4+1] = f32x2{w0.z, w0.w};
            W2p[ks*4+2] = f32x2{w1.x, w1.y};
            W2p[ks*4+3] = f32x2{w1.z, w1.w};
        }
    }
    // W2 B-fragments: bf[nt][ks] elem i = W2[ks*32+hi*8+i][nt*16+lo16]
    short8 bf[4][3];
#pragma unroll
    for (int nt = 0; nt < 4; ++nt)
#pragma unroll
        for (int ks = 0; ks < 3; ++ks) {
            float v[8];
#pragma unroll
            for (int i = 0; i < 8; ++i)
                v[i] = W2[(size_t)(ks * 32 + hi * 8 + i) * FOUT + nt * 16 + lo16];
            union { unsigned u[4]; short8 s8; } cv;
            cv.u[0] = pack_bf16(v[0], v[1]);
            cv.u[1] = pack_bf16(v[2], v[3]);
            cv.u[2] = pack_bf16(v[4], v[5]);
            cv.u[3] = pack_bf16(v[6], v[7]);
            bf[nt][ks] = cv.s8;
        }

    float c2[4], corr[4];
#pragma unroll
    for (int nt = 0; nt < 4; ++nt) {
        c2[nt] = TWO_LOG2E * b2[nt * 16 + lo16];
        corr[nt] = 0.5f - RCPF(1.f + EXP2F(c2[nt]));
    }

    __syncthreads();   // sA ready

    float Rs[NG][4];
#pragma unroll
    for (int nl = 0; nl < NG; ++nl)
#pragma unroll
        for (int nt = 0; nt < 4; ++nt) Rs[nl][nt] = 0.f;

    // wave w owns row-tiles {2w, 2w+1}: rows m = (2w+it)*16 + lo16
    int m0 = (2 * w) * 16 + lo16;         // always < 255
    int m1 = (2 * w + 1) * 16 + lo16;     // ==255 only for w=7,lo16=15

#pragma unroll 1
    for (int nl = 0; nl < NG; ++nl) {
        int n = n0 + nl;
        int bn = (b << 8) + n;

        // A slices from sA (broadcast LDS reads)
        f32x2 A2[12];
#pragma unroll
        for (int ks = 0; ks < 3; ++ks) {
            const float* ap = &sA[nl][ks * 32 + hi * 8];
            float4 a0 = *(const float4*)(ap);
            float4 a1 = *(const float4*)(ap + 4);
            A2[ks*4+0] = f32x2{a0.x, a0.y};
            A2[ks*4+1] = f32x2{a0.z, a0.w};
            A2[ks*4+2] = f32x2{a1.x, a1.y};
            A2[ks*4+3] = f32x2{a1.z, a1.w};
        }

        const float* eg = edge + (size_t)bn * (NN - 1);
        float ev[2];
        ev[0] = eg[m0];
        ev[1] = eg[m1 < NN - 1 ? m1 : NN - 2];

        // C-slice register double buffer (it=0 preload)
        uint4 q0, q1, q2;
        {
            int j = m0 + (m0 >= n);
            const unsigned short* crow = &sC[j * CPAD + hi * 8];
            q0 = *(const uint4*)(crow);
            q1 = *(const uint4*)(crow + 32);
            q2 = *(const uint4*)(crow + 64);
        }

#pragma unroll
        for (int it = 0; it < 2; ++it) {
            uint4 p0, p1, p2;
            if (it == 0) {
                int jn = m1 + (m1 >= n);
                jn = (jn > 255) ? 255 : jn;
                const unsigned short* crow = &sC[jn * CPAD + hi * 8];
                p0 = *(const uint4*)(crow);
                p1 = *(const uint4*)(crow + 32);
                p2 = *(const uint4*)(crow + 64);
            }

            f32x2 e2 = f32x2{ev[it], ev[it]};
            uint4 qs[3] = {q0, q1, q2};

            short8 af[3];
#pragma unroll
            for (int ks = 0; ks < 3; ++ks) {
                unsigned uu[4] = {qs[ks].x, qs[ks].y, qs[ks].z, qs[ks].w};
                unsigned ro[4];
#pragma unroll
                for (int p = 0; p < 4; ++p) {
                    f32x2 c;
                    c.x = __uint_as_float(uu[p] << 16);
                    c.y = __uint_as_float(uu[p] & 0xFFFF0000u);
                    f32x2 s = pk_add(A2[ks*4+p], c);
                    f32x2 h = pk_fma(e2, W2p[ks*4+p], s);
                    ro[p] = pack_bf16(fmaxf(h.x, 0.f), fmaxf(h.y, 0.f));
                }
                union { unsigned u[4]; short8 s8; } cv;
                cv.u[0] = ro[0]; cv.u[1] = ro[1]; cv.u[2] = ro[2]; cv.u[3] = ro[3];
                af[ks] = cv.s8;
            }

            // invalid slot: m==255 -> it=1, w=7, lo16=15
            if (it == 1 && w == 7 && lo16 == 15) {
                af[0] = (short8)0; af[1] = (short8)0; af[2] = (short8)0;
            }

            f32x4 acc[4] = {{0.f,0.f,0.f,0.f},{0.f,0.f,0.f,0.f},
                            {0.f,0.f,0.f,0.f},{0.f,0.f,0.f,0.f}};
#pragma unroll
            for (int ks = 0; ks < 3; ++ks)
#pragma unroll
                for (int nt = 0; nt < 4; ++nt)
                    acc[nt] = __builtin_amdgcn_mfma_f32_16x16x32_bf16(
                        af[ks], bf[nt][ks], acc[nt], 0, 0, 0);

#pragma unroll
            for (int nt = 0; nt < 4; ++nt)
#pragma unroll
                for (int r4 = 0; r4 < 4; ++r4) {
                    float arg = fmaf(acc[nt][r4], TWO_LOG2E, c2[nt]);
                    Rs[nl][nt] += RCPF(1.f + EXP2F(arg));
                }

            if (it == 0) { q0 = p0; q1 = p1; q2 = p2; }
        }

        // invalid slot correction (tile 15, D-row 255 -> w=7, hi=3)
        if (w == 7 && hi == 3) {
#pragma unroll
            for (int nt = 0; nt < 4; ++nt) Rs[nl][nt] += corr[nt];
        }
    }

    // ---- final reduction: overlay on sC (all sC reads are done) ----
    __syncthreads();
    float* s_red = (float*)sC;   // [NG][8 waves][64] = 16 KB
#pragma unroll
    for (int nl = 0; nl < NG; ++nl)
#pragma unroll
        for (int nt = 0; nt < 4; ++nt) {
            float v = Rs[nl][nt];
            v += __shfl_xor(v, 16);
            v += __shfl_xor(v, 32);
            Rs[nl][nt] = v;
        }
    if (hi == 0) {
#pragma unroll
        for (int nl = 0; nl < NG; ++nl)
#pragma unroll
            for (int nt = 0; nt < 4; ++nt)
                s_red[(nl * 8 + w) * 64 + nt * 16 + lo16] = Rs[nl][nt];
    }
    __syncthreads();
    {
        int onl = tid >> 6, oo = tid & 63;   // 512 threads = 8 nl x 64 cols
        float t = 0.f;
#pragma unroll
        for (int ww = 0; ww < 8; ++ww)
            t += s_red[(onl * 8 + ww) * 64 + oo];
        out[(size_t)((b << 8) + n0 + onl) * FOUT + oo] = fmaf(-2.f, t, 256.f);
    }
}

extern "C" void kernel_launch(void* const* d_in, const int* in_sizes, int n_in,
                              void* d_out, int out_size, void* d_ws, size_t ws_size,
                              hipStream_t stream) {
    const float* inp_node = (const float*)d_in[0];  // (8,256,64)
    const float* inp_edge = (const float*)d_in[1];  // (8,256,255)
    const float* W1       = (const float*)d_in[2];  // (129,96)
    const float* b1       = (const float*)d_in[3];  // (96,)
    const float* W2       = (const float*)d_in[4];  // (96,64)
    const float* b2       = (const float*)d_in[5];  // (64,)
    float* out            = (float*)d_out;          // (8,256,64)

    // single fused kernel; d_ws unused
    edge_fused8<<<BATCH * (NN / NG), 512, 0, stream>>>(
        inp_node, inp_edge, W1, b1, W2, b2, out);
}